// Round 1
// baseline (174.428 us; speedup 1.0000x reference)
//
#include <hip/hip_runtime.h>
#include <math.h>

#define D 20
#define RPT 4  // rows per thread

// Workspace layout: two fp64 accumulators + folded constants.
struct Ws {
  double sum_h;
  double sum_abs;
  float M1t[D * D];  // M1t[j][d] = sum_e W[e][d] * W_init[e][j]   (transposed for contiguous d-reads)
  float c[D];        // c[j] = sum_e b[e] * W_init[e][j] + 1
};

// One tiny block: fold the first two linears into (M1, c), zero accumulators.
__global__ void prep_kernel(const float* __restrict__ W,
                            const float* __restrict__ b,
                            const float* __restrict__ Wi,
                            Ws* __restrict__ ws) {
  int t = threadIdx.x;
  if (t < D * D) {
    int j = t / D, d = t % D;
    float acc = 0.f;
#pragma unroll
    for (int e = 0; e < D; ++e) acc = fmaf(W[e * D + d], Wi[e * D + j], acc);
    ws->M1t[t] = acc;
  } else if (t < D * D + D) {
    int j = t - D * D;
    float acc = 1.0f;
#pragma unroll
    for (int e = 0; e < D; ++e) acc = fmaf(b[e], Wi[e * D + j], acc);
    ws->c[j] = acc;
  } else if (t == D * D + D) {
    ws->sum_h = 0.0;
    ws->sum_abs = 0.0;
  }
}

// Main fused kernel: per row compute h2 = relu(x@M1 + c), h3 = h2@W^T + b,
// accumulate sum(h3) and sum(|h3|). Never materializes [B,D].
__global__ __launch_bounds__(256, 2) void fused_kernel(
    const float* __restrict__ X,
    const float* __restrict__ W,
    const float* __restrict__ b,
    Ws* __restrict__ ws,
    int nrows) {
  __shared__ float sM1t[D * D];
  __shared__ float sW[D * D];
  __shared__ float sc[D];
  __shared__ float sb[D];
  __shared__ float sred[8];

  const int t = threadIdx.x;
  for (int i = t; i < D * D; i += 256) {
    sM1t[i] = ws->M1t[i];
    sW[i] = W[i];
  }
  if (t < D) {
    sc[t] = ws->c[t];
    sb[t] = b[t];
  }
  __syncthreads();

  float rs = 0.f, ra = 0.f;
  const long long row0 = ((long long)blockIdx.x * 256 + t) * RPT;
  // nrows = 1e6 is divisible by RPT=4, so row0 < nrows implies all RPT rows valid.
  if (row0 < nrows) {
    // Load RPT*D = 80 floats (80 bytes/row, 16B-aligned) as float4s.
    float xf[RPT * D];
    const float4* __restrict__ Xv = (const float4*)(X + row0 * D);
#pragma unroll
    for (int i = 0; i < (RPT * D) / 4; ++i) {
      float4 v = Xv[i];
      xf[4 * i + 0] = v.x;
      xf[4 * i + 1] = v.y;
      xf[4 * i + 2] = v.z;
      xf[4 * i + 3] = v.w;
    }

    // Stage 1: h2[r][j] = relu(sum_d x[r][d] * M1t[j][d] + c[j])
    float h2[RPT][D];
#pragma unroll
    for (int j = 0; j < D; ++j) {
      float a0 = sc[j], a1 = a0, a2 = a0, a3 = a0;
#pragma unroll
      for (int d = 0; d < D; ++d) {
        const float m = sM1t[j * D + d];  // broadcast LDS read, contiguous in d -> b128
        a0 = fmaf(xf[0 * D + d], m, a0);
        a1 = fmaf(xf[1 * D + d], m, a1);
        a2 = fmaf(xf[2 * D + d], m, a2);
        a3 = fmaf(xf[3 * D + d], m, a3);
      }
      h2[0][j] = fmaxf(a0, 0.f);
      h2[1][j] = fmaxf(a1, 0.f);
      h2[2][j] = fmaxf(a2, 0.f);
      h2[3][j] = fmaxf(a3, 0.f);
    }

    // Stage 2: h3[r][j2] = sum_j h2[r][j] * W[j2][j] + b[j2]; accumulate sums.
#pragma unroll
    for (int j2 = 0; j2 < D; ++j2) {
      float a0 = sb[j2], a1 = a0, a2 = a0, a3 = a0;
#pragma unroll
      for (int j = 0; j < D; ++j) {
        const float w = sW[j2 * D + j];
        a0 = fmaf(h2[0][j], w, a0);
        a1 = fmaf(h2[1][j], w, a1);
        a2 = fmaf(h2[2][j], w, a2);
        a3 = fmaf(h2[3][j], w, a3);
      }
      rs += a0 + a1 + a2 + a3;
      ra += fabsf(a0) + fabsf(a1) + fabsf(a2) + fabsf(a3);
    }
  }

  // Wave (64-lane) reduction, then cross-wave via LDS, one fp64 atomic per block.
#pragma unroll
  for (int off = 32; off > 0; off >>= 1) {
    rs += __shfl_down(rs, off, 64);
    ra += __shfl_down(ra, off, 64);
  }
  const int wave = t >> 6, lane = t & 63;
  if (lane == 0) {
    sred[wave] = rs;
    sred[4 + wave] = ra;
  }
  __syncthreads();
  if (t == 0) {
    float s1 = sred[0] + sred[1] + sred[2] + sred[3];
    float s2 = sred[4] + sred[5] + sred[6] + sred[7];
    atomicAdd(&ws->sum_h, (double)s1);
    atomicAdd(&ws->sum_abs, (double)s2);
  }
}

// Single-thread finalize: count halvings of sum(|h|), scale sum(h) by 2^-k.
__global__ void fin_kernel(const Ws* __restrict__ ws, float* __restrict__ out) {
  double s = ws->sum_abs;
  int k = 0;
  while (s > 1.0 && k < 1100) {
    s *= 0.5;
    ++k;
  }
  out[0] = ldexpf((float)ws->sum_h, -k);
}

extern "C" void kernel_launch(void* const* d_in, const int* in_sizes, int n_in,
                              void* d_out, int out_size, void* d_ws, size_t ws_size,
                              hipStream_t stream) {
  const float* X = (const float*)d_in[0];
  const float* W = (const float*)d_in[1];
  const float* b = (const float*)d_in[2];
  const float* Wi = (const float*)d_in[3];
  float* out = (float*)d_out;
  Ws* ws = (Ws*)d_ws;

  const int nrows = in_sizes[0] / D;  // 1,000,000

  hipLaunchKernelGGL(prep_kernel, dim3(1), dim3(512), 0, stream, W, b, Wi, ws);

  const int nthreads = (nrows + RPT - 1) / RPT;
  const int nblocks = (nthreads + 255) / 256;
  hipLaunchKernelGGL(fused_kernel, dim3(nblocks), dim3(256), 0, stream, X, W, b, ws, nrows);

  hipLaunchKernelGGL(fin_kernel, dim3(1), dim3(1), 0, stream, ws, out);
}

// Round 2
// 161.991 us; speedup vs baseline: 1.0768x; 1.0768x over previous
//
#include <hip/hip_runtime.h>
#include <math.h>

#define D 20
#define RPT 2  // rows per thread

// d_ws layout:
//   [0..15]        two doubles: acc[0]=sum_h, acc[1]=sum_abs
//   [64..1663]     M1t[400] floats : M1t[j*D+d] = sum_e W[e][d]*W_init[e][j]
//   [1664..1743]   c[20] floats    : c[j] = sum_e b[e]*W_init[e][j] + 1
#define WS_M1T_OFF 16   // in floats (64 bytes)
#define WS_C_OFF 416    // in floats (1664 bytes)

// One tiny block: fold the first two linears into (M1t, c), zero accumulators.
__global__ void prep_kernel(const float* __restrict__ W,
                            const float* __restrict__ b,
                            const float* __restrict__ Wi,
                            float* __restrict__ wsf) {
  int t = threadIdx.x;
  if (t < D * D) {
    int j = t / D, d = t % D;
    float acc = 0.f;
#pragma unroll
    for (int e = 0; e < D; ++e) acc = fmaf(W[e * D + d], Wi[e * D + j], acc);
    wsf[WS_M1T_OFF + t] = acc;
  } else if (t < D * D + D) {
    int j = t - D * D;
    float acc = 1.0f;
#pragma unroll
    for (int e = 0; e < D; ++e) acc = fmaf(b[e], Wi[e * D + j], acc);
    wsf[WS_C_OFF + j] = acc;
  } else if (t == D * D + D) {
    double* acc = (double*)wsf;
    acc[0] = 0.0;
    acc[1] = 0.0;
  }
}

// Main fused kernel. Per row: h2 = relu(x@M1 + c); h3 = h2@W^T + b;
// accumulate sum(h3), sum(|h3|). Constants are read with thread-uniform
// addresses from global -> compiler emits s_load into SGPRs (K$-cached),
// so the inner FMAs are v_fma_f32 vgpr,vgpr,sgpr with no LDS traffic.
// RPT=2 keeps the live set (~40 xf + 40 h2) under ~100 VGPRs -> no spills.
__global__ __launch_bounds__(256, 4) void fused_kernel(
    const float* __restrict__ X,
    const float* __restrict__ W,
    const float* __restrict__ b,
    const float* __restrict__ M1t,
    const float* __restrict__ c,
    double* __restrict__ acc,
    int nrows) {
  const int t = threadIdx.x;
  float rs = 0.f, ra = 0.f;

  const long long row0 = ((long long)blockIdx.x * 256 + t) * RPT;
  if (row0 < nrows) {  // nrows % RPT == 0, so both rows valid
    // 2 rows * 20 floats = 160 contiguous bytes, 16B-aligned -> 10 float4s.
    float xf[RPT * D];
    const float4* __restrict__ Xv = (const float4*)(X + row0 * D);
#pragma unroll
    for (int i = 0; i < (RPT * D) / 4; ++i) {
      float4 v = Xv[i];
      xf[4 * i + 0] = v.x;
      xf[4 * i + 1] = v.y;
      xf[4 * i + 2] = v.z;
      xf[4 * i + 3] = v.w;
    }

    // Stage 1: h2[r][j] = relu(sum_d xf[r][d] * M1t[j][d] + c[j]).
    // j-iterations are independent -> ILP across the unroll.
    float h2[RPT][D];
#pragma unroll
    for (int j = 0; j < D; ++j) {
      float a0 = c[j], a1 = a0;
#pragma unroll
      for (int d = 0; d < D; ++d) {
        const float m = M1t[j * D + d];  // uniform -> SGPR
        a0 = fmaf(xf[d], m, a0);
        a1 = fmaf(xf[D + d], m, a1);
      }
      h2[0][j] = fmaxf(a0, 0.f);
      h2[1][j] = fmaxf(a1, 0.f);
    }

    // Stage 2: h3[r][j2] = sum_j h2[r][j] * W[j2][j] + b[j2]; reduce on the fly.
#pragma unroll
    for (int j2 = 0; j2 < D; ++j2) {
      float a0 = b[j2], a1 = a0;
#pragma unroll
      for (int j = 0; j < D; ++j) {
        const float w = W[j2 * D + j];  // uniform -> SGPR
        a0 = fmaf(h2[0][j], w, a0);
        a1 = fmaf(h2[1][j], w, a1);
      }
      rs += a0 + a1;
      ra += fabsf(a0) + fabsf(a1);
    }
  }

  // Wave (64-lane) shuffle reduction, cross-wave via LDS, 1 fp64 atomic/block.
  __shared__ float sred[8];
#pragma unroll
  for (int off = 32; off > 0; off >>= 1) {
    rs += __shfl_down(rs, off, 64);
    ra += __shfl_down(ra, off, 64);
  }
  const int wave = t >> 6, lane = t & 63;
  if (lane == 0) {
    sred[wave] = rs;
    sred[4 + wave] = ra;
  }
  __syncthreads();
  if (t == 0) {
    float s1 = sred[0] + sred[1] + sred[2] + sred[3];
    float s2 = sred[4] + sred[5] + sred[6] + sred[7];
    atomicAdd(&acc[0], (double)s1);
    atomicAdd(&acc[1], (double)s2);
  }
}

// Single-thread finalize: count halvings of sum(|h|), scale sum(h) by 2^-k.
__global__ void fin_kernel(const double* __restrict__ acc, float* __restrict__ out) {
  double s = acc[1];
  int k = 0;
  while (s > 1.0 && k < 1100) {
    s *= 0.5;
    ++k;
  }
  out[0] = ldexpf((float)acc[0], -k);
}

extern "C" void kernel_launch(void* const* d_in, const int* in_sizes, int n_in,
                              void* d_out, int out_size, void* d_ws, size_t ws_size,
                              hipStream_t stream) {
  const float* X = (const float*)d_in[0];
  const float* W = (const float*)d_in[1];
  const float* b = (const float*)d_in[2];
  const float* Wi = (const float*)d_in[3];
  float* out = (float*)d_out;
  float* wsf = (float*)d_ws;
  double* acc = (double*)d_ws;
  const float* M1t = wsf + WS_M1T_OFF;
  const float* c = wsf + WS_C_OFF;

  const int nrows = in_sizes[0] / D;  // 1,000,000

  hipLaunchKernelGGL(prep_kernel, dim3(1), dim3(512), 0, stream, W, b, Wi, wsf);

  const int nthreads = (nrows + RPT - 1) / RPT;
  const int nblocks = (nthreads + 255) / 256;
  hipLaunchKernelGGL(fused_kernel, dim3(nblocks), dim3(256), 0, stream,
                     X, W, b, M1t, c, acc, nrows);

  hipLaunchKernelGGL(fin_kernel, dim3(1), dim3(1), 0, stream, acc, out);
}